// Round 1
// baseline (3523.959 us; speedup 1.0000x reference)
//
#include <hip/hip_runtime.h>

#define HW40 1600

// ---------------------------------------------------------------------------
// Weight transpose:  wt[cin*K + tap][co] = w[co][cin*K + tap]
// ---------------------------------------------------------------------------
__global__ void transpose_w_kernel(const float* __restrict__ w, float* __restrict__ wt,
                                   int Cout, int CinK) {
  int idx = blockIdx.x * 256 + threadIdx.x;
  if (idx >= Cout * CinK) return;
  int co = idx % Cout;
  int ck = idx / Cout;
  wt[idx] = w[(size_t)co * CinK + ck];
}

// ---------------------------------------------------------------------------
// com conv: 3x3 s1 p1, Cin=256 -> Cout=48 on 40x40.
// Writes om[b][48][40][40]; channels 32..47 pass through sigmoid (mask).
// grid = B*40 (one (b,h) row per block), block = 256 (240 active compute).
// thread tile: 4 cout x 2 px.
// ---------------------------------------------------------------------------
__global__ __launch_bounds__(256) void conv3x3_com(const float* __restrict__ x,
                                                   const float* __restrict__ wt,
                                                   const float* __restrict__ bias,
                                                   float* __restrict__ om) {
  const int b = blockIdx.x / 40;
  const int h = blockIdx.x % 40;
  const int t = threadIdx.x;
  __shared__ float sx[32 * 136];  // [cin][3][44]; col c at index c+1 (cols -1..40)
  const int cog = t % 12;
  const int pg  = t / 12;          // 0..19 for t<240
  const int co0 = cog * 4;
  const int p0  = pg * 2;
  const bool active = (t < 240);
  float acc[4][2] = {{0.f, 0.f}, {0.f, 0.f}, {0.f, 0.f}, {0.f, 0.f}};
  const float* xb = x + (size_t)b * 256 * HW40;

  for (int c0 = 0; c0 < 256; c0 += 32) {
    __syncthreads();
    for (int e = t; e < 32 * 126; e += 256) {
      int c   = e / 126;
      int rem = e - c * 126;
      int r   = (rem >= 84) ? 2 : (rem >= 42 ? 1 : 0);
      int cc  = rem - r * 42;
      int col = cc - 1;
      int y   = h - 1 + r;
      float v = 0.f;
      if (col >= 0 && col < 40 && y >= 0 && y < 40)
        v = xb[(size_t)(c0 + c) * HW40 + y * 40 + col];
      sx[c * 136 + r * 44 + cc] = v;
    }
    __syncthreads();
    if (active) {
      for (int c = 0; c < 32; ++c) {
        const float* wp  = wt + ((size_t)(c0 + c) * 9) * 48 + co0;
        const float* sxp = sx + c * 136;
#pragma unroll
        for (int r = 0; r < 3; ++r) {
          float2 xab = *(const float2*)(sxp + r * 44 + p0);
          float2 xcd = *(const float2*)(sxp + r * 44 + p0 + 2);
          float xr[4] = {xab.x, xab.y, xcd.x, xcd.y};
#pragma unroll
          for (int kx = 0; kx < 3; ++kx) {
            float4 w4 = *(const float4*)(wp + (r * 3 + kx) * 48);
            acc[0][0] += w4.x * xr[kx]; acc[0][1] += w4.x * xr[kx + 1];
            acc[1][0] += w4.y * xr[kx]; acc[1][1] += w4.y * xr[kx + 1];
            acc[2][0] += w4.z * xr[kx]; acc[2][1] += w4.z * xr[kx + 1];
            acc[3][0] += w4.w * xr[kx]; acc[3][1] += w4.w * xr[kx + 1];
          }
        }
      }
    }
  }
  if (active) {
#pragma unroll
    for (int cc = 0; cc < 4; ++cc) {
      int co = co0 + cc;
      float bv = bias[co];
#pragma unroll
      for (int pp = 0; pp < 2; ++pp) {
        float v = acc[cc][pp] + bv;
        if (co >= 32) v = 1.f / (1.f + expf(-v));
        om[((size_t)(b * 48 + co) * 40 + h) * 40 + (p0 + pp)] = v;
      }
    }
  }
}

// ---------------------------------------------------------------------------
// Deformable conv (modulated, zero-pad bilinear) fused with relu + residual.
// x: [B,256,Hin,Win]; om: [B,48,40,40] (offsets raw, mask sigmoided);
// wt: [cin*16 + i][256] transposed dcn weights.
// f_dst = relu(dc + bias) + f_src   (in-place safe: 1 thread per element)
// grid = (100, B), block = 128.  Per i: sample col[256][16] -> GEMM 8co x 4px.
// ---------------------------------------------------------------------------
#define FMA4(A, s, c) \
  A.x += (s) * (c).x; A.y += (s) * (c).y; A.z += (s) * (c).z; A.w += (s) * (c).w;

__global__ __launch_bounds__(128) void deform_kernel(
    const float* __restrict__ x, const float* __restrict__ om,
    const float* __restrict__ wt, const float* __restrict__ bias,
    const float* __restrict__ f_src, float* __restrict__ f_dst,
    int Hin, int Win, int stride, int pad, int dil) {
  const int b = blockIdx.y;
  const int tile = blockIdx.x;
  const int t = threadIdx.x;
  __shared__ float col[256 * 16];
  const int HWin = Hin * Win;
  // sampling role
  const int sp = t & 15;
  const int p_lin = tile * 16 + sp;
  const int ph = p_lin / 40;
  const int pw = p_lin - ph * 40;
  const int scin0 = t >> 4;  // 0..7
  // gemm role
  const int co0 = (t & 31) * 8;
  const int pb  = (t >> 5) * 4;

  float4 accv[8];
#pragma unroll
  for (int k = 0; k < 8; ++k) accv[k] = make_float4(0.f, 0.f, 0.f, 0.f);

  const float* xb  = x + (size_t)b * 256 * HWin;
  const float* omb = om + (size_t)b * 48 * HW40 + p_lin;

  for (int i = 0; i < 16; ++i) {
    // --- geometry (per-thread, for its sampling pixel) ---
    float dy = omb[(2 * i) * HW40];
    float dx = omb[(2 * i + 1) * HW40];
    float mz = omb[(32 + i) * HW40];
    float py = (float)(ph * stride - pad + (i >> 2) * dil) + dy;
    float px = (float)(pw * stride - pad + (i & 3) * dil) + dx;
    float y0f = floorf(py), x0f = floorf(px);
    float ly = py - y0f, lx = px - x0f;
    int y0 = (int)y0f, x0 = (int)x0f;
    int y1 = y0 + 1, x1 = x0 + 1;
    float hy = 1.f - ly, hx = 1.f - lx;
    float w00 = hy * hx * mz, w01 = hy * lx * mz;
    float w10 = ly * hx * mz, w11 = ly * lx * mz;
    if (y0 < 0 || y0 >= Hin) { w00 = 0.f; w01 = 0.f; }
    if (y1 < 0 || y1 >= Hin) { w10 = 0.f; w11 = 0.f; }
    if (x0 < 0 || x0 >= Win) { w00 = 0.f; w10 = 0.f; }
    if (x1 < 0 || x1 >= Win) { w01 = 0.f; w11 = 0.f; }
    int cy0 = min(max(y0, 0), Hin - 1), cy1 = min(max(y1, 0), Hin - 1);
    int cx0 = min(max(x0, 0), Win - 1), cx1 = min(max(x1, 0), Win - 1);
    int l00 = cy0 * Win + cx0, l01 = cy0 * Win + cx1;
    int l10 = cy1 * Win + cx0, l11 = cy1 * Win + cx1;

    __syncthreads();  // previous GEMM readers done before col overwrite
    // --- sampling: 256 cin x 16 px / 128 thr = 32 samples each ---
#pragma unroll 4
    for (int j = 0; j < 32; ++j) {
      int cin = scin0 + j * 8;
      const float* xp = xb + (size_t)cin * HWin;
      float v = w00 * xp[l00] + w01 * xp[l01] + w10 * xp[l10] + w11 * xp[l11];
      col[cin * 16 + sp] = v;
    }
    __syncthreads();

    // --- GEMM over cin for this tap ---
    const float* wp = wt + (size_t)i * 256 + co0;  // [(cin*16+i)*256 + co]
    const float* cp = col + pb;
#pragma unroll 4
    for (int cin = 0; cin < 256; ++cin) {
      const float* w8 = wp + (size_t)cin * 4096;
      float4 wa = *(const float4*)(w8);
      float4 wb = *(const float4*)(w8 + 4);
      float4 c4 = *(const float4*)(cp + cin * 16);
      FMA4(accv[0], wa.x, c4); FMA4(accv[1], wa.y, c4);
      FMA4(accv[2], wa.z, c4); FMA4(accv[3], wa.w, c4);
      FMA4(accv[4], wb.x, c4); FMA4(accv[5], wb.y, c4);
      FMA4(accv[6], wb.z, c4); FMA4(accv[7], wb.w, c4);
    }
  }

#pragma unroll
  for (int cc = 0; cc < 8; ++cc) {
    int co = co0 + cc;
    float bv = bias[co];
    size_t base = ((size_t)b * 256 + co) * HW40 + tile * 16 + pb;
    float vals[4] = {accv[cc].x, accv[cc].y, accv[cc].z, accv[cc].w};
#pragma unroll
    for (int pp = 0; pp < 4; ++pp) {
      float dc = vals[pp] + bv;
      f_dst[base + pp] = fmaxf(dc, 0.f) + f_src[base + pp];
    }
  }
}

// ---------------------------------------------------------------------------
// res conv: 3x3 s1 p1, 256 -> 256, out = fh + conv(f) + bias.
// grid = B*40*2 (co halves), block = 256; thread tile 4co x 5px.
// ---------------------------------------------------------------------------
__global__ __launch_bounds__(256) void conv3x3_res(const float* __restrict__ x,
                                                   const float* __restrict__ wt,
                                                   const float* __restrict__ bias,
                                                   const float* __restrict__ fh,
                                                   float* __restrict__ out) {
  const int bx = blockIdx.x;
  const int b = bx / 80;
  const int rem = bx % 80;
  const int h = rem >> 1;
  const int half = rem & 1;
  const int t = threadIdx.x;
  __shared__ float sx[32 * 136];
  const int co0 = half * 128 + (t & 31) * 4;
  const int pg = t >> 5;  // 0..7
  const int p0 = pg * 5;
  float acc[4][5] = {};
  const float* xb = x + (size_t)b * 256 * HW40;

  for (int c0 = 0; c0 < 256; c0 += 32) {
    __syncthreads();
    for (int e = t; e < 32 * 126; e += 256) {
      int c   = e / 126;
      int rem2 = e - c * 126;
      int r   = (rem2 >= 84) ? 2 : (rem2 >= 42 ? 1 : 0);
      int cc  = rem2 - r * 42;
      int col = cc - 1;
      int y   = h - 1 + r;
      float v = 0.f;
      if (col >= 0 && col < 40 && y >= 0 && y < 40)
        v = xb[(size_t)(c0 + c) * HW40 + y * 40 + col];
      sx[c * 136 + r * 44 + cc] = v;
    }
    __syncthreads();
    for (int c = 0; c < 32; ++c) {
      const float* wp  = wt + ((size_t)(c0 + c) * 9) * 256 + co0;
      const float* sxp = sx + c * 136;
#pragma unroll
      for (int r = 0; r < 3; ++r) {
        float xr[7];
#pragma unroll
        for (int q = 0; q < 7; ++q) xr[q] = sxp[r * 44 + p0 + q];
#pragma unroll
        for (int kx = 0; kx < 3; ++kx) {
          float4 w4 = *(const float4*)(wp + (r * 3 + kx) * 256);
#pragma unroll
          for (int pp = 0; pp < 5; ++pp) {
            acc[0][pp] += w4.x * xr[kx + pp];
            acc[1][pp] += w4.y * xr[kx + pp];
            acc[2][pp] += w4.z * xr[kx + pp];
            acc[3][pp] += w4.w * xr[kx + pp];
          }
        }
      }
    }
  }
#pragma unroll
  for (int cc = 0; cc < 4; ++cc) {
    int co = co0 + cc;
    float bv = bias[co];
    size_t base = ((size_t)(b * 256 + co) * 40 + h) * 40 + p0;
#pragma unroll
    for (int pp = 0; pp < 5; ++pp) {
      out[base + pp] = acc[cc][pp] + bv + fh[base + pp];
    }
  }
}

// ---------------------------------------------------------------------------
extern "C" void kernel_launch(void* const* d_in, const int* in_sizes, int n_in,
                              void* d_out, int out_size, void* d_ws, size_t ws_size,
                              hipStream_t stream) {
  (void)in_sizes; (void)n_in; (void)out_size; (void)ws_size;
  const float* f0     = (const float*)d_in[0];
  const float* f1     = (const float*)d_in[1];
  const float* f2     = (const float*)d_in[2];
  const float* com_w0 = (const float*)d_in[3];
  const float* com_b0 = (const float*)d_in[4];
  const float* com_w1 = (const float*)d_in[5];
  const float* com_b1 = (const float*)d_in[6];
  const float* dcn_w0 = (const float*)d_in[7];
  const float* dcn_b0 = (const float*)d_in[8];
  const float* dcn_w1 = (const float*)d_in[9];
  const float* dcn_b1 = (const float*)d_in[10];
  const float* res_w  = (const float*)d_in[11];
  const float* res_b  = (const float*)d_in[12];
  float* out = (float*)d_out;
  float* ws  = (float*)d_ws;

  // ws layout (floats): total ~4.95M floats = 19.8 MB
  float* om   = ws + 0;        // 307,200
  float* fbuf = ws + 320000;   // 1,638,400
  float* cw0  = ws + 2000000;  // 110,592
  float* cw1  = ws + 2120000;  // 110,592
  float* cwr  = ws + 2240000;  // 589,824
  float* wd0  = ws + 2840000;  // 1,048,576
  float* wd1  = ws + 3900000;  // 1,048,576

  transpose_w_kernel<<<(48 * 2304 + 255) / 256, 256, 0, stream>>>(com_w0, cw0, 48, 2304);
  transpose_w_kernel<<<(48 * 2304 + 255) / 256, 256, 0, stream>>>(com_w1, cw1, 48, 2304);
  transpose_w_kernel<<<(256 * 2304 + 255) / 256, 256, 0, stream>>>(res_w, cwr, 256, 2304);
  transpose_w_kernel<<<(256 * 4096 + 255) / 256, 256, 0, stream>>>(dcn_w0, wd0, 256, 4096);
  transpose_w_kernel<<<(256 * 4096 + 255) / 256, 256, 0, stream>>>(dcn_w1, wd1, 256, 4096);

  const float* fsrc = f2;
  for (int s = 0; s < 4; ++s) {
    int l = s & 1;
    conv3x3_com<<<4 * 40, 256, 0, stream>>>(fsrc, l ? cw1 : cw0, l ? com_b1 : com_b0, om);
    if (l == 0) {
      // level 0: sample f1 (80x80), k=4, stride=2, pad=1, dil=1
      deform_kernel<<<dim3(100, 4), 128, 0, stream>>>(f1, om, wd0, dcn_b0, fsrc, fbuf,
                                                      80, 80, 2, 1, 1);
    } else {
      // level 1: sample f0 (160x160), k=4, stride=4, pad=3, dil=3
      deform_kernel<<<dim3(100, 4), 128, 0, stream>>>(f0, om, wd1, dcn_b1, fsrc, fbuf,
                                                      160, 160, 4, 3, 3);
    }
    fsrc = fbuf;
  }
  conv3x3_res<<<4 * 80, 256, 0, stream>>>(fbuf, cwr, res_b, f2, out);
}

// Round 2
// 1640.844 us; speedup vs baseline: 2.1477x; 2.1477x over previous
//
#include <hip/hip_runtime.h>

#define HW40 1600
typedef unsigned short ushort_t;
typedef __attribute__((ext_vector_type(8))) short short8;
typedef __attribute__((ext_vector_type(4))) float f4v;

__device__ __forceinline__ float bu(ushort_t u) {
  union { unsigned i; float f; } x; x.i = ((unsigned)u) << 16; return x.f;
}
__device__ __forceinline__ ushort_t fb(float f) {
  union { float f; unsigned i; } x; x.f = f;
  unsigned r = x.i + 0x7FFFu + ((x.i >> 16) & 1u);
  return (ushort_t)(r >> 16);
}

#define GLD16(g, l)                                                            \
  __builtin_amdgcn_global_load_lds(                                            \
      (const __attribute__((address_space(1))) void*)(g),                      \
      (__attribute__((address_space(3))) void*)(l), 16, 0, 0)

// ---------------------------------------------------------------------------
// Weight transpose (fp32):  wt[cin*K + tap][co] = w[co][cin*K + tap]
// ---------------------------------------------------------------------------
__global__ void transpose_w_kernel(const float* __restrict__ w, float* __restrict__ wt,
                                   int Cout, int CinK) {
  int idx = blockIdx.x * 256 + threadIdx.x;
  if (idx >= Cout * CinK) return;
  int co = idx % Cout;
  int ck = idx / Cout;
  wt[idx] = w[(size_t)co * CinK + ck];
}

// ---------------------------------------------------------------------------
// dcn weights [co][cin][16] fp32 -> A_bf16 [co][k = i*256 + cin]
// grid 512 (co for w0, then co for w1), block 256.
// ---------------------------------------------------------------------------
__global__ __launch_bounds__(256) void convert_dcnw(const float* __restrict__ w0,
                                                    const float* __restrict__ w1,
                                                    ushort_t* __restrict__ A0,
                                                    ushort_t* __restrict__ A1) {
  __shared__ float s[4096];
  const int co = blockIdx.x & 255;
  const float* w = (blockIdx.x < 256) ? w0 : w1;
  ushort_t* A = (blockIdx.x < 256) ? A0 : A1;
  const int t = threadIdx.x;
  const float4* wp = (const float4*)(w + (size_t)co * 4096);
#pragma unroll
  for (int q = 0; q < 4; ++q) ((float4*)s)[t + q * 256] = wp[t + q * 256];
  __syncthreads();
  // out element o = t*16 + j : tap i = t>>4 (const per thread), cin = (t&15)*16 + j
  const int i = t >> 4, cb = (t & 15) * 16;
  ushort_t tmp[16];
#pragma unroll
  for (int j = 0; j < 16; ++j) tmp[j] = fb(s[(cb + j) * 16 + i]);
  ushort_t* op = A + (size_t)co * 4096 + t * 16;
  ((uint4*)op)[0] = ((uint4*)tmp)[0];
  ((uint4*)op)[1] = ((uint4*)tmp)[1];
}

// ---------------------------------------------------------------------------
// NCHW fp32 -> NHWC bf16:  xt[b][s][c] = bf16(x[b][c][s])
// grid (HW/32, 8, B), block 256 (32x8 tile workers), LDS 32x33 pad.
// ---------------------------------------------------------------------------
__global__ __launch_bounds__(256) void nhwc_bf16_kernel(const float* __restrict__ x,
                                                        ushort_t* __restrict__ xt, int HW) {
  __shared__ float tile[32][33];
  const int s0 = blockIdx.x * 32, c0 = blockIdx.y * 32, b = blockIdx.z;
  const int tx = threadIdx.x & 31, ty = threadIdx.x >> 5;
  const float* xb = x + ((size_t)b * 256 + c0) * HW + s0;
#pragma unroll
  for (int q = 0; q < 4; ++q) tile[ty + q * 8][tx] = xb[(size_t)(ty + q * 8) * HW + tx];
  __syncthreads();
  ushort_t* ob = xt + ((size_t)b * HW + s0) * 256 + c0;
#pragma unroll
  for (int q = 0; q < 4; ++q) {
    int srow = ty + q * 8;
    ob[(size_t)srow * 256 + tx] = fb(tile[tx][srow]);
  }
}

// ---------------------------------------------------------------------------
// com conv: 3x3 s1 p1, 256 -> 48 on 40x40 (unchanged from R1).
// ---------------------------------------------------------------------------
__global__ __launch_bounds__(256) void conv3x3_com(const float* __restrict__ x,
                                                   const float* __restrict__ wt,
                                                   const float* __restrict__ bias,
                                                   float* __restrict__ om) {
  const int b = blockIdx.x / 40;
  const int h = blockIdx.x % 40;
  const int t = threadIdx.x;
  __shared__ float sx[32 * 136];
  const int cog = t % 12;
  const int pg  = t / 12;
  const int co0 = cog * 4;
  const int p0  = pg * 2;
  const bool active = (t < 240);
  float acc[4][2] = {{0.f, 0.f}, {0.f, 0.f}, {0.f, 0.f}, {0.f, 0.f}};
  const float* xb = x + (size_t)b * 256 * HW40;

  for (int c0 = 0; c0 < 256; c0 += 32) {
    __syncthreads();
    for (int e = t; e < 32 * 126; e += 256) {
      int c   = e / 126;
      int rem = e - c * 126;
      int r   = (rem >= 84) ? 2 : (rem >= 42 ? 1 : 0);
      int cc  = rem - r * 42;
      int col = cc - 1;
      int y   = h - 1 + r;
      float v = 0.f;
      if (col >= 0 && col < 40 && y >= 0 && y < 40)
        v = xb[(size_t)(c0 + c) * HW40 + y * 40 + col];
      sx[c * 136 + r * 44 + cc] = v;
    }
    __syncthreads();
    if (active) {
      for (int c = 0; c < 32; ++c) {
        const float* wp  = wt + ((size_t)(c0 + c) * 9) * 48 + co0;
        const float* sxp = sx + c * 136;
#pragma unroll
        for (int r = 0; r < 3; ++r) {
          float2 xab = *(const float2*)(sxp + r * 44 + p0);
          float2 xcd = *(const float2*)(sxp + r * 44 + p0 + 2);
          float xr[4] = {xab.x, xab.y, xcd.x, xcd.y};
#pragma unroll
          for (int kx = 0; kx < 3; ++kx) {
            float4 w4 = *(const float4*)(wp + (r * 3 + kx) * 48);
            acc[0][0] += w4.x * xr[kx]; acc[0][1] += w4.x * xr[kx + 1];
            acc[1][0] += w4.y * xr[kx]; acc[1][1] += w4.y * xr[kx + 1];
            acc[2][0] += w4.z * xr[kx]; acc[2][1] += w4.z * xr[kx + 1];
            acc[3][0] += w4.w * xr[kx]; acc[3][1] += w4.w * xr[kx + 1];
          }
        }
      }
    }
  }
  if (active) {
#pragma unroll
    for (int cc = 0; cc < 4; ++cc) {
      int co = co0 + cc;
      float bv = bias[co];
#pragma unroll
      for (int pp = 0; pp < 2; ++pp) {
        float v = acc[cc][pp] + bv;
        if (co >= 32) v = 1.f / (1.f + expf(-v));
        om[((size_t)(b * 48 + co) * 40 + h) * 40 + (p0 + pp)] = v;
      }
    }
  }
}

// ---------------------------------------------------------------------------
// Sampler: builds colT[n = b*1600+px][k = i*256+cin] bf16 via bilinear gather
// from NHWC-bf16 xt. grid (100 px-tiles of 16, B), block 256.
// ---------------------------------------------------------------------------
__global__ __launch_bounds__(256) void sample_kernel(
    const ushort_t* __restrict__ xt, const float* __restrict__ om,
    ushort_t* __restrict__ colT, int Hin, int Win, int stride, int pad, int dil) {
  __shared__ int4  gL[256];
  __shared__ float4 gW[256];
  const int b = blockIdx.y;
  const int px0 = blockIdx.x * 16;
  const int t = threadIdx.x;
  const int HWin = Hin * Win;

  {  // geometry: pair pid = t -> (px_l = t&15, tap i = t>>4)
    const int px_l = t & 15, i = t >> 4;
    const int p = px0 + px_l;
    const int ph = p / 40, pw = p - (p / 40) * 40;
    const float* omb = om + (size_t)b * 48 * HW40 + p;
    float dy = omb[(2 * i) * HW40];
    float dx = omb[(2 * i + 1) * HW40];
    float mz = omb[(32 + i) * HW40];
    float py = (float)(ph * stride - pad + (i >> 2) * dil) + dy;
    float px = (float)(pw * stride - pad + (i & 3) * dil) + dx;
    float y0f = floorf(py), x0f = floorf(px);
    float ly = py - y0f, lx = px - x0f;
    int y0 = (int)y0f, x0 = (int)x0f;
    int y1 = y0 + 1, x1 = x0 + 1;
    float hy = 1.f - ly, hx = 1.f - lx;
    float w00 = hy * hx * mz, w01 = hy * lx * mz;
    float w10 = ly * hx * mz, w11 = ly * lx * mz;
    if (y0 < 0 || y0 >= Hin) { w00 = 0.f; w01 = 0.f; }
    if (y1 < 0 || y1 >= Hin) { w10 = 0.f; w11 = 0.f; }
    if (x0 < 0 || x0 >= Win) { w00 = 0.f; w10 = 0.f; }
    if (x1 < 0 || x1 >= Win) { w01 = 0.f; w11 = 0.f; }
    int cy0 = min(max(y0, 0), Hin - 1), cy1 = min(max(y1, 0), Hin - 1);
    int cx0 = min(max(x0, 0), Win - 1), cx1 = min(max(x1, 0), Win - 1);
    gL[t] = make_int4((cy0 * Win + cx0) * 256, (cy0 * Win + cx1) * 256,
                      (cy1 * Win + cx0) * 256, (cy1 * Win + cx1) * 256);
    gW[t] = make_float4(w00, w01, w10, w11);
  }
  __syncthreads();

  const ushort_t* xtb = xt + (size_t)b * HWin * 256;
  const int wv = t >> 6, l = t & 63;
  const int half = l >> 5;
  const int cin8 = (l & 31) * 8;

#pragma unroll 2
  for (int it = 0; it < 32; ++it) {
    const int pr = it * 8 + wv * 2 + half;
    const int4 G = gL[pr];
    const float4 W = gW[pr];
    short8 c00 = *(const short8*)(xtb + G.x + cin8);
    short8 c01 = *(const short8*)(xtb + G.y + cin8);
    short8 c10 = *(const short8*)(xtb + G.z + cin8);
    short8 c11 = *(const short8*)(xtb + G.w + cin8);
    short8 r;
#pragma unroll
    for (int j = 0; j < 8; ++j) {
      float v = W.x * bu((ushort_t)c00[j]) + W.y * bu((ushort_t)c01[j]) +
                W.z * bu((ushort_t)c10[j]) + W.w * bu((ushort_t)c11[j]);
      r[j] = (short)fb(v);
    }
    const int px_l = pr & 15, i = pr >> 4;
    *(short8*)(colT + ((size_t)(b * 1600 + px0 + px_l) * 4096 + i * 256 + cin8)) = r;
  }
}

// ---------------------------------------------------------------------------
// bf16 MFMA GEMM, split-K=2: part[kz][co][n] = sum_k A[co][k] * colT[n][k]
// grid (nt=50, mt=2, kz=2), block 256 (4 waves, 2x2 of 64x64 wave tiles).
// m97 structure: global_load_lds width 16, BK=32, 16x16x32 bf16 MFMA.
// ---------------------------------------------------------------------------
__global__ __launch_bounds__(256) void gemm_deform(const ushort_t* __restrict__ A,
                                                   const ushort_t* __restrict__ colT,
                                                   float* __restrict__ part) {
  __shared__ ushort_t sA[128 * 32];
  __shared__ ushort_t sB[128 * 32];
  const int nt = blockIdx.x, mt = blockIdx.y, kz = blockIdx.z;
  const int t = threadIdx.x;
  const int wv = t >> 6, l = t & 63;
  const int wm = wv >> 1, wn = wv & 1;

  f4v acc[4][4];
#pragma unroll
  for (int a = 0; a < 4; ++a)
#pragma unroll
    for (int bb = 0; bb < 4; ++bb) acc[a][bb] = (f4v)(0.f);

  const int c0 = t, c1 = t + 256;  // 16B chunks: row = c>>2, sub = c&3
  const size_t aoff0 = (size_t)(mt * 128 + (c0 >> 2)) * 4096 + (c0 & 3) * 8;
  const size_t aoff1 = (size_t)(mt * 128 + (c1 >> 2)) * 4096 + (c1 & 3) * 8;
  const size_t boff0 = (size_t)(nt * 128 + (c0 >> 2)) * 4096 + (c0 & 3) * 8;
  const size_t boff1 = (size_t)(nt * 128 + (c1 >> 2)) * 4096 + (c1 & 3) * 8;
  ushort_t* lA0 = sA + c0 * 8;  ushort_t* lA1 = sA + c1 * 8;
  ushort_t* lB0 = sB + c0 * 8;  ushort_t* lB1 = sB + c1 * 8;

  int k0 = kz * 2048;
  const int kq = (l >> 4) * 8;
  const int lm = l & 15;

  for (int step = 0; step < 64; ++step, k0 += 32) {
    __syncthreads();
    GLD16(A + aoff0 + k0, lA0);
    GLD16(A + aoff1 + k0, lA1);
    GLD16(colT + boff0 + k0, lB0);
    GLD16(colT + boff1 + k0, lB1);
    __syncthreads();
    short8 af[4], bfr[4];
#pragma unroll
    for (int fm = 0; fm < 4; ++fm)
      af[fm] = *(const short8*)(sA + (wm * 64 + fm * 16 + lm) * 32 + kq);
#pragma unroll
    for (int fn = 0; fn < 4; ++fn)
      bfr[fn] = *(const short8*)(sB + (wn * 64 + fn * 16 + lm) * 32 + kq);
#pragma unroll
    for (int fm = 0; fm < 4; ++fm)
#pragma unroll
      for (int fn = 0; fn < 4; ++fn)
        acc[fm][fn] = __builtin_amdgcn_mfma_f32_16x16x32_bf16(af[fm], bfr[fn],
                                                              acc[fm][fn], 0, 0, 0);
  }

  const int row_l = (l >> 4) * 4;
  float* pb = part + (size_t)kz * 1638400;
#pragma unroll
  for (int fm = 0; fm < 4; ++fm) {
#pragma unroll
    for (int fn = 0; fn < 4; ++fn) {
      int n = nt * 128 + wn * 64 + fn * 16 + lm;
#pragma unroll
      for (int r = 0; r < 4; ++r) {
        int co = mt * 128 + wm * 64 + fm * 16 + row_l + r;
        pb[(size_t)co * 6400 + n] = acc[fm][fn][r];
      }
    }
  }
}

// ---------------------------------------------------------------------------
// Epilogue: f_dst = relu(P0 + P1 + bias) + f_src   grid (2, 256co, B)
// ---------------------------------------------------------------------------
__global__ __launch_bounds__(256) void deform_epilogue(const float* __restrict__ part,
                                                       const float* __restrict__ bias,
                                                       const float* __restrict__ fsrc,
                                                       float* __restrict__ fdst) {
  const int co = blockIdx.y, b = blockIdx.z;
  const int idx = blockIdx.x * 256 + threadIdx.x;
  if (idx >= 400) return;
  const int p = idx * 4;
  const size_t n = (size_t)b * 1600 + p;
  float4 a = *(const float4*)(part + (size_t)co * 6400 + n);
  float4 c = *(const float4*)(part + 1638400 + (size_t)co * 6400 + n);
  float bv = bias[co];
  const size_t fo = ((size_t)b * 256 + co) * 1600 + p;
  float4 s = *(const float4*)(fsrc + fo);
  float4 o;
  o.x = fmaxf(a.x + c.x + bv, 0.f) + s.x;
  o.y = fmaxf(a.y + c.y + bv, 0.f) + s.y;
  o.z = fmaxf(a.z + c.z + bv, 0.f) + s.z;
  o.w = fmaxf(a.w + c.w + bv, 0.f) + s.w;
  *(float4*)(fdst + fo) = o;
}

// ---------------------------------------------------------------------------
// res conv: 3x3 s1 p1, 256 -> 256, out = fh + conv(f) + bias (unchanged).
// ---------------------------------------------------------------------------
__global__ __launch_bounds__(256) void conv3x3_res(const float* __restrict__ x,
                                                   const float* __restrict__ wt,
                                                   const float* __restrict__ bias,
                                                   const float* __restrict__ fh,
                                                   float* __restrict__ out) {
  const int bx = blockIdx.x;
  const int b = bx / 80;
  const int rem = bx % 80;
  const int h = rem >> 1;
  const int half = rem & 1;
  const int t = threadIdx.x;
  __shared__ float sx[32 * 136];
  const int co0 = half * 128 + (t & 31) * 4;
  const int pg = t >> 5;
  const int p0 = pg * 5;
  float acc[4][5] = {};
  const float* xb = x + (size_t)b * 256 * HW40;

  for (int c0 = 0; c0 < 256; c0 += 32) {
    __syncthreads();
    for (int e = t; e < 32 * 126; e += 256) {
      int c   = e / 126;
      int rem2 = e - c * 126;
      int r   = (rem2 >= 84) ? 2 : (rem2 >= 42 ? 1 : 0);
      int cc  = rem2 - r * 42;
      int col = cc - 1;
      int y   = h - 1 + r;
      float v = 0.f;
      if (col >= 0 && col < 40 && y >= 0 && y < 40)
        v = xb[(size_t)(c0 + c) * HW40 + y * 40 + col];
      sx[c * 136 + r * 44 + cc] = v;
    }
    __syncthreads();
    for (int c = 0; c < 32; ++c) {
      const float* wp  = wt + ((size_t)(c0 + c) * 9) * 256 + co0;
      const float* sxp = sx + c * 136;
#pragma unroll
      for (int r = 0; r < 3; ++r) {
        float xr[7];
#pragma unroll
        for (int q = 0; q < 7; ++q) xr[q] = sxp[r * 44 + p0 + q];
#pragma unroll
        for (int kx = 0; kx < 3; ++kx) {
          float4 w4 = *(const float4*)(wp + (r * 3 + kx) * 256);
#pragma unroll
          for (int pp = 0; pp < 5; ++pp) {
            acc[0][pp] += w4.x * xr[kx + pp];
            acc[1][pp] += w4.y * xr[kx + pp];
            acc[2][pp] += w4.z * xr[kx + pp];
            acc[3][pp] += w4.w * xr[kx + pp];
          }
        }
      }
    }
  }
#pragma unroll
  for (int cc = 0; cc < 4; ++cc) {
    int co = co0 + cc;
    float bv = bias[co];
    size_t base = ((size_t)(b * 256 + co) * 40 + h) * 40 + p0;
#pragma unroll
    for (int pp = 0; pp < 5; ++pp) {
      out[base + pp] = acc[cc][pp] + bv + fh[base + pp];
    }
  }
}

// ---------------------------------------------------------------------------
extern "C" void kernel_launch(void* const* d_in, const int* in_sizes, int n_in,
                              void* d_out, int out_size, void* d_ws, size_t ws_size,
                              hipStream_t stream) {
  (void)in_sizes; (void)n_in; (void)out_size; (void)ws_size;
  const float* f0     = (const float*)d_in[0];
  const float* f1     = (const float*)d_in[1];
  const float* f2     = (const float*)d_in[2];
  const float* com_w0 = (const float*)d_in[3];
  const float* com_b0 = (const float*)d_in[4];
  const float* com_w1 = (const float*)d_in[5];
  const float* com_b1 = (const float*)d_in[6];
  const float* dcn_w0 = (const float*)d_in[7];
  const float* dcn_b0 = (const float*)d_in[8];
  const float* dcn_w1 = (const float*)d_in[9];
  const float* dcn_b1 = (const float*)d_in[10];
  const float* res_w  = (const float*)d_in[11];
  const float* res_b  = (const float*)d_in[12];
  float* out = (float*)d_out;
  float* ws  = (float*)d_ws;

  // ws layout (float offsets); total ~36.7M floats ~= 147 MB
  float*    om   = ws + 0;         //   307,200
  float*    fbuf = ws + 310000;    // 1,638,400
  float*    cw0  = ws + 1950000;   //   110,592
  float*    cw1  = ws + 2070000;   //   110,592
  float*    cwr  = ws + 2190000;   //   589,824
  ushort_t* A0   = (ushort_t*)(ws + 2790000);   // 1,048,576 u16
  ushort_t* A1   = (ushort_t*)(ws + 3320000);   // 1,048,576 u16
  ushort_t* f1t  = (ushort_t*)(ws + 3850000);   // 6,553,600 u16
  ushort_t* f0t  = (ushort_t*)(ws + 7130000);   // 26,214,400 u16
  ushort_t* colT = (ushort_t*)(ws + 20240000);  // 26,214,400 u16
  float*    part = ws + 33350000;               // 3,276,800 f32

  transpose_w_kernel<<<(48 * 2304 + 255) / 256, 256, 0, stream>>>(com_w0, cw0, 48, 2304);
  transpose_w_kernel<<<(48 * 2304 + 255) / 256, 256, 0, stream>>>(com_w1, cw1, 48, 2304);
  transpose_w_kernel<<<(256 * 2304 + 255) / 256, 256, 0, stream>>>(res_w, cwr, 256, 2304);
  convert_dcnw<<<512, 256, 0, stream>>>(dcn_w0, dcn_w1, A0, A1);
  nhwc_bf16_kernel<<<dim3(200, 8, 4), 256, 0, stream>>>(f1, f1t, 6400);
  nhwc_bf16_kernel<<<dim3(800, 8, 4), 256, 0, stream>>>(f0, f0t, 25600);

  const float* fsrc = f2;
  for (int s = 0; s < 4; ++s) {
    int l = s & 1;
    conv3x3_com<<<4 * 40, 256, 0, stream>>>(fsrc, l ? cw1 : cw0, l ? com_b1 : com_b0, om);
    if (l == 0) {
      sample_kernel<<<dim3(100, 4), 256, 0, stream>>>(f1t, om, colT, 80, 80, 2, 1, 1);
    } else {
      sample_kernel<<<dim3(100, 4), 256, 0, stream>>>(f0t, om, colT, 160, 160, 4, 3, 3);
    }
    gemm_deform<<<dim3(50, 2, 2), 256, 0, stream>>>(l ? A1 : A0, colT, part);
    deform_epilogue<<<dim3(2, 256, 4), 256, 0, stream>>>(part, l ? dcn_b1 : dcn_b0, fsrc, fbuf);
    fsrc = fbuf;
  }
  conv3x3_res<<<4 * 80, 256, 0, stream>>>(fbuf, cwr, res_b, f2, out);
}

// Round 3
// 832.485 us; speedup vs baseline: 4.2331x; 1.9710x over previous
//
#include <hip/hip_runtime.h>

#define HW40 1600
typedef unsigned short ushort_t;
typedef __attribute__((ext_vector_type(8))) short short8;
typedef __attribute__((ext_vector_type(4))) float f4v;

__device__ __forceinline__ float bu(ushort_t u) {
  union { unsigned i; float f; } x; x.i = ((unsigned)u) << 16; return x.f;
}
__device__ __forceinline__ ushort_t fb(float f) {
  union { float f; unsigned i; } x; x.f = f;
  unsigned r = x.i + 0x7FFFu + ((x.i >> 16) & 1u);
  return (ushort_t)(r >> 16);
}

#define GLD16(g, l)                                                            \
  __builtin_amdgcn_global_load_lds(                                            \
      (const __attribute__((address_space(1))) void*)(g),                      \
      (__attribute__((address_space(3))) void*)(l), 16, 0, 0)

// ---------------------------------------------------------------------------
// 3x3 conv weights [co][cin][3][3] fp32 -> A[co][tap*256+cin] bf16,
// zero-padded to Cout_pad rows.
// ---------------------------------------------------------------------------
__global__ void convert_w9(const float* __restrict__ src, ushort_t* __restrict__ dst,
                           int Cout_src, int Cout_pad) {
  int idx = blockIdx.x * 256 + threadIdx.x;
  if (idx >= Cout_pad * 2304) return;
  int co = idx / 2304;
  int k  = idx - co * 2304;
  int cin = k & 255, tap = k >> 8;
  dst[idx] = (co < Cout_src) ? fb(src[(size_t)co * 2304 + cin * 9 + tap]) : (ushort_t)0;
}

// ---------------------------------------------------------------------------
// dcn weights [co][cin][16] fp32 -> A_bf16 [co][k = i*256 + cin]
// ---------------------------------------------------------------------------
__global__ __launch_bounds__(256) void convert_dcnw(const float* __restrict__ w0,
                                                    const float* __restrict__ w1,
                                                    ushort_t* __restrict__ A0,
                                                    ushort_t* __restrict__ A1) {
  __shared__ float s[4096];
  const int co = blockIdx.x & 255;
  const float* w = (blockIdx.x < 256) ? w0 : w1;
  ushort_t* A = (blockIdx.x < 256) ? A0 : A1;
  const int t = threadIdx.x;
  const float4* wp = (const float4*)(w + (size_t)co * 4096);
#pragma unroll
  for (int q = 0; q < 4; ++q) ((float4*)s)[t + q * 256] = wp[t + q * 256];
  __syncthreads();
  const int i = t >> 4, cb = (t & 15) * 16;
  ushort_t tmp[16];
#pragma unroll
  for (int j = 0; j < 16; ++j) tmp[j] = fb(s[(cb + j) * 16 + i]);
  ushort_t* op = A + (size_t)co * 4096 + t * 16;
  ((uint4*)op)[0] = ((uint4*)tmp)[0];
  ((uint4*)op)[1] = ((uint4*)tmp)[1];
}

// ---------------------------------------------------------------------------
// NCHW fp32 -> NHWC bf16:  xt[b][s][c] = bf16(x[b][c][s])
// grid (HW/32, 8, B), block 256, LDS 32x33 pad.
// ---------------------------------------------------------------------------
__global__ __launch_bounds__(256) void nhwc_bf16_kernel(const float* __restrict__ x,
                                                        ushort_t* __restrict__ xt, int HW) {
  __shared__ float tile[32][33];
  const int s0 = blockIdx.x * 32, c0 = blockIdx.y * 32, b = blockIdx.z;
  const int tx = threadIdx.x & 31, ty = threadIdx.x >> 5;
  const float* xb = x + ((size_t)b * 256 + c0) * HW + s0;
#pragma unroll
  for (int q = 0; q < 4; ++q) tile[ty + q * 8][tx] = xb[(size_t)(ty + q * 8) * HW + tx];
  __syncthreads();
  ushort_t* ob = xt + ((size_t)b * HW + s0) * 256 + c0;
#pragma unroll
  for (int q = 0; q < 4; ++q) {
    int srow = ty + q * 8;
    ob[(size_t)srow * 256 + tx] = fb(tile[tx][srow]);
  }
}

// ---------------------------------------------------------------------------
// im2col for 3x3 s1 p1 on 40x40 NHWC-bf16 feature:
// colC[(b*1600+px)][tap*256+c] = ft[b][(ph+ky-1)*40+(pw+kx-1)][c] (0 if OOB)
// grid (100 px-tiles of 16, B), block 256.
// ---------------------------------------------------------------------------
__global__ __launch_bounds__(256) void im2col40(const ushort_t* __restrict__ ft,
                                                ushort_t* __restrict__ colC) {
  const int b = blockIdx.y;
  const int px0 = blockIdx.x * 16;
  const int t = threadIdx.x;
  const int c8 = (t & 31) * 8;
  const int r  = t >> 5;  // 0..7
  const ushort_t* fb_ = ft + (size_t)b * 1600 * 256;
#pragma unroll 2
  for (int it = 0; it < 18; ++it) {
    int rc = it * 8 + r;            // 0..143 = px_l*9 + tap
    int px_l = rc / 9;
    int tap  = rc - px_l * 9;
    int p  = px0 + px_l;
    int ph = p / 40, pw = p - (p / 40) * 40;
    int ky = tap / 3, kx = tap - (tap / 3) * 3;
    int y = ph + ky - 1, xq = pw + kx - 1;
    short8 v = (short8)(0);
    if (y >= 0 && y < 40 && xq >= 0 && xq < 40)
      v = *(const short8*)(fb_ + (size_t)(y * 40 + xq) * 256 + c8);
    *(short8*)(colC + ((size_t)(b * 1600 + p) * 2304 + tap * 256 + c8)) = v;
  }
}

// ---------------------------------------------------------------------------
// Sampler: builds colT[n = b*1600+px][k = i*256+cin] bf16 via bilinear gather
// from NHWC-bf16 xt. grid (100 px-tiles of 16, B), block 256.
// ---------------------------------------------------------------------------
__global__ __launch_bounds__(256) void sample_kernel(
    const ushort_t* __restrict__ xt, const float* __restrict__ om,
    ushort_t* __restrict__ colT, int Hin, int Win, int stride, int pad, int dil) {
  __shared__ int4  gL[256];
  __shared__ float4 gW[256];
  const int b = blockIdx.y;
  const int px0 = blockIdx.x * 16;
  const int t = threadIdx.x;
  const int HWin = Hin * Win;

  {
    const int px_l = t & 15, i = t >> 4;
    const int p = px0 + px_l;
    const int ph = p / 40, pw = p - (p / 40) * 40;
    const float* omb = om + (size_t)b * 48 * HW40 + p;
    float dy = omb[(2 * i) * HW40];
    float dx = omb[(2 * i + 1) * HW40];
    float mz = omb[(32 + i) * HW40];
    float py = (float)(ph * stride - pad + (i >> 2) * dil) + dy;
    float px = (float)(pw * stride - pad + (i & 3) * dil) + dx;
    float y0f = floorf(py), x0f = floorf(px);
    float ly = py - y0f, lx = px - x0f;
    int y0 = (int)y0f, x0 = (int)x0f;
    int y1 = y0 + 1, x1 = x0 + 1;
    float hy = 1.f - ly, hx = 1.f - lx;
    float w00 = hy * hx * mz, w01 = hy * lx * mz;
    float w10 = ly * hx * mz, w11 = ly * lx * mz;
    if (y0 < 0 || y0 >= Hin) { w00 = 0.f; w01 = 0.f; }
    if (y1 < 0 || y1 >= Hin) { w10 = 0.f; w11 = 0.f; }
    if (x0 < 0 || x0 >= Win) { w00 = 0.f; w10 = 0.f; }
    if (x1 < 0 || x1 >= Win) { w01 = 0.f; w11 = 0.f; }
    int cy0 = min(max(y0, 0), Hin - 1), cy1 = min(max(y1, 0), Hin - 1);
    int cx0 = min(max(x0, 0), Win - 1), cx1 = min(max(x1, 0), Win - 1);
    gL[t] = make_int4((cy0 * Win + cx0) * 256, (cy0 * Win + cx1) * 256,
                      (cy1 * Win + cx0) * 256, (cy1 * Win + cx1) * 256);
    gW[t] = make_float4(w00, w01, w10, w11);
  }
  __syncthreads();

  const ushort_t* xtb = xt + (size_t)b * HWin * 256;
  const int wv = t >> 6, l = t & 63;
  const int half = l >> 5;
  const int cin8 = (l & 31) * 8;

#pragma unroll 2
  for (int it = 0; it < 32; ++it) {
    const int pr = it * 8 + wv * 2 + half;
    const int4 G = gL[pr];
    const float4 W = gW[pr];
    short8 c00 = *(const short8*)(xtb + G.x + cin8);
    short8 c01 = *(const short8*)(xtb + G.y + cin8);
    short8 c10 = *(const short8*)(xtb + G.z + cin8);
    short8 c11 = *(const short8*)(xtb + G.w + cin8);
    short8 rr;
#pragma unroll
    for (int j = 0; j < 8; ++j) {
      float v = W.x * bu((ushort_t)c00[j]) + W.y * bu((ushort_t)c01[j]) +
                W.z * bu((ushort_t)c10[j]) + W.w * bu((ushort_t)c11[j]);
      rr[j] = (short)fb(v);
    }
    const int px_l = pr & 15, i = pr >> 4;
    *(short8*)(colT + ((size_t)(b * 1600 + px0 + px_l) * 4096 + i * 256 + cin8)) = rr;
  }
}

// ---------------------------------------------------------------------------
// Generic bf16 MFMA GEMM, split-K=2:
//   part[kz][m][n] += A[m][k] * B[n][k],  m-tile 128 (gridDim.y), n-tile 128.
// K = row stride (elements), ksteps = K/(2*32) per kz slice.
// grid (50, M/128, 2), block 256.
// ---------------------------------------------------------------------------
__global__ __launch_bounds__(256) void gemm_bt(const ushort_t* __restrict__ A,
                                               const ushort_t* __restrict__ B,
                                               float* __restrict__ part,
                                               int ksteps, int K) {
  __shared__ ushort_t sA[128 * 32];
  __shared__ ushort_t sB[128 * 32];
  const int nt = blockIdx.x, mt = blockIdx.y, kz = blockIdx.z;
  const int t = threadIdx.x;
  const int wv = t >> 6, l = t & 63;
  const int wm = wv >> 1, wn = wv & 1;

  f4v acc[4][4];
#pragma unroll
  for (int a = 0; a < 4; ++a)
#pragma unroll
    for (int bb = 0; bb < 4; ++bb) acc[a][bb] = (f4v)(0.f);

  const int c0 = t, c1 = t + 256;
  const size_t aoff0 = (size_t)(mt * 128 + (c0 >> 2)) * K + (c0 & 3) * 8;
  const size_t aoff1 = (size_t)(mt * 128 + (c1 >> 2)) * K + (c1 & 3) * 8;
  const size_t boff0 = (size_t)(nt * 128 + (c0 >> 2)) * K + (c0 & 3) * 8;
  const size_t boff1 = (size_t)(nt * 128 + (c1 >> 2)) * K + (c1 & 3) * 8;
  ushort_t* lA0 = sA + c0 * 8;  ushort_t* lA1 = sA + c1 * 8;
  ushort_t* lB0 = sB + c0 * 8;  ushort_t* lB1 = sB + c1 * 8;

  int k0 = kz * ksteps * 32;
  const int kq = (l >> 4) * 8;
  const int lm = l & 15;

  for (int step = 0; step < ksteps; ++step, k0 += 32) {
    __syncthreads();
    GLD16(A + aoff0 + k0, lA0);
    GLD16(A + aoff1 + k0, lA1);
    GLD16(B + boff0 + k0, lB0);
    GLD16(B + boff1 + k0, lB1);
    __syncthreads();
    short8 af[4], bfr[4];
#pragma unroll
    for (int fm = 0; fm < 4; ++fm)
      af[fm] = *(const short8*)(sA + (wm * 64 + fm * 16 + lm) * 32 + kq);
#pragma unroll
    for (int fn = 0; fn < 4; ++fn)
      bfr[fn] = *(const short8*)(sB + (wn * 64 + fn * 16 + lm) * 32 + kq);
#pragma unroll
    for (int fm = 0; fm < 4; ++fm)
#pragma unroll
      for (int fn = 0; fn < 4; ++fn)
        acc[fm][fn] = __builtin_amdgcn_mfma_f32_16x16x32_bf16(af[fm], bfr[fn],
                                                              acc[fm][fn], 0, 0, 0);
  }

  const int row_l = (l >> 4) * 4;
  float* pb = part + (size_t)kz * 1638400;
#pragma unroll
  for (int fm = 0; fm < 4; ++fm) {
#pragma unroll
    for (int fn = 0; fn < 4; ++fn) {
      int n = nt * 128 + wn * 64 + fn * 16 + lm;
#pragma unroll
      for (int r = 0; r < 4; ++r) {
        int m = mt * 128 + wm * 64 + fm * 16 + row_l + r;
        pb[(size_t)m * 6400 + n] = acc[fm][fn][r];
      }
    }
  }
}

// ---------------------------------------------------------------------------
// com epilogue: om[(b*48+co)*1600+px] = act(P0+P1+bias), sigmoid for co>=32.
// grid (25, 48), block 256.
// ---------------------------------------------------------------------------
__global__ __launch_bounds__(256) void com_epilogue(const float* __restrict__ part,
                                                    const float* __restrict__ bias,
                                                    float* __restrict__ om) {
  const int co = blockIdx.y;
  const int n = blockIdx.x * 256 + threadIdx.x;
  const int b = n / 1600, px = n - b * 1600;
  float v = part[(size_t)co * 6400 + n] + part[1638400 + (size_t)co * 6400 + n] + bias[co];
  if (co >= 32) v = 1.f / (1.f + expf(-v));
  om[((size_t)b * 48 + co) * 1600 + px] = v;
}

// ---------------------------------------------------------------------------
// GEMM epilogue: dst = (relu? max(P0+P1+bias,0) : P0+P1+bias) + src
// grid (2, 256, B), block 256.
// ---------------------------------------------------------------------------
__global__ __launch_bounds__(256) void gemm_epilogue(const float* __restrict__ part,
                                                     const float* __restrict__ bias,
                                                     const float* __restrict__ src,
                                                     float* __restrict__ dst, int relu) {
  const int co = blockIdx.y, b = blockIdx.z;
  const int idx = blockIdx.x * 256 + threadIdx.x;
  if (idx >= 400) return;
  const int p = idx * 4;
  const size_t n = (size_t)b * 1600 + p;
  float4 a = *(const float4*)(part + (size_t)co * 6400 + n);
  float4 c = *(const float4*)(part + 1638400 + (size_t)co * 6400 + n);
  float bv = bias[co];
  const size_t fo = ((size_t)b * 256 + co) * 1600 + p;
  float4 s = *(const float4*)(src + fo);
  float4 o;
  if (relu) {
    o.x = fmaxf(a.x + c.x + bv, 0.f) + s.x;
    o.y = fmaxf(a.y + c.y + bv, 0.f) + s.y;
    o.z = fmaxf(a.z + c.z + bv, 0.f) + s.z;
    o.w = fmaxf(a.w + c.w + bv, 0.f) + s.w;
  } else {
    o.x = a.x + c.x + bv + s.x;
    o.y = a.y + c.y + bv + s.y;
    o.z = a.z + c.z + bv + s.z;
    o.w = a.w + c.w + bv + s.w;
  }
  *(float4*)(dst + fo) = o;
}

// ---------------------------------------------------------------------------
extern "C" void kernel_launch(void* const* d_in, const int* in_sizes, int n_in,
                              void* d_out, int out_size, void* d_ws, size_t ws_size,
                              hipStream_t stream) {
  (void)in_sizes; (void)n_in; (void)out_size; (void)ws_size;
  const float* f0     = (const float*)d_in[0];
  const float* f1     = (const float*)d_in[1];
  const float* f2     = (const float*)d_in[2];
  const float* com_w0 = (const float*)d_in[3];
  const float* com_b0 = (const float*)d_in[4];
  const float* com_w1 = (const float*)d_in[5];
  const float* com_b1 = (const float*)d_in[6];
  const float* dcn_w0 = (const float*)d_in[7];
  const float* dcn_b0 = (const float*)d_in[8];
  const float* dcn_w1 = (const float*)d_in[9];
  const float* dcn_b1 = (const float*)d_in[10];
  const float* res_w  = (const float*)d_in[11];
  const float* res_b  = (const float*)d_in[12];
  float* out = (float*)d_out;
  float* ws  = (float*)d_ws;

  // ws layout (float offsets); total ~37.2M floats ~= 149 MB
  float*    om    = ws + 0;          //   307,200
  float*    fbuf  = ws + 310000;     // 1,638,400
  ushort_t* A0    = (ushort_t*)(ws + 1950000);   // 1,048,576 u16
  ushort_t* A1    = (ushort_t*)(ws + 2480000);   // 1,048,576 u16
  ushort_t* Acom0 = (ushort_t*)(ws + 3010000);   //   294,912 u16 (128x2304)
  ushort_t* Acom1 = (ushort_t*)(ws + 3160000);   //   294,912 u16
  ushort_t* Ares  = (ushort_t*)(ws + 3310000);   //   589,824 u16 (256x2304)
  ushort_t* ft40  = (ushort_t*)(ws + 3610000);   // 1,638,400 u16
  ushort_t* f1t   = (ushort_t*)(ws + 4430000);   // 6,553,600 u16
  ushort_t* f0t   = (ushort_t*)(ws + 7710000);   // 26,214,400 u16
  ushort_t* colB  = (ushort_t*)(ws + 20820000);  // 26,214,400 u16 (colC & colT share)
  float*    part  = ws + 33930000;               // 3,276,800 f32

  convert_w9<<<(128 * 2304 + 255) / 256, 256, 0, stream>>>(com_w0, Acom0, 48, 128);
  convert_w9<<<(128 * 2304 + 255) / 256, 256, 0, stream>>>(com_w1, Acom1, 48, 128);
  convert_w9<<<(256 * 2304 + 255) / 256, 256, 0, stream>>>(res_w, Ares, 256, 256);
  convert_dcnw<<<512, 256, 0, stream>>>(dcn_w0, dcn_w1, A0, A1);
  nhwc_bf16_kernel<<<dim3(200, 8, 4), 256, 0, stream>>>(f1, f1t, 6400);
  nhwc_bf16_kernel<<<dim3(800, 8, 4), 256, 0, stream>>>(f0, f0t, 25600);

  const float* fsrc = f2;
  for (int s = 0; s < 4; ++s) {
    int l = s & 1;
    // com conv as GEMM (M=48 padded to 128, K=2304)
    nhwc_bf16_kernel<<<dim3(50, 8, 4), 256, 0, stream>>>(fsrc, ft40, 1600);
    im2col40<<<dim3(100, 4), 256, 0, stream>>>(ft40, colB);
    gemm_bt<<<dim3(50, 1, 2), 256, 0, stream>>>(l ? Acom1 : Acom0, colB, part, 36, 2304);
    com_epilogue<<<dim3(25, 48), 256, 0, stream>>>(part, l ? com_b1 : com_b0, om);
    // deformable conv (K=4096)
    if (l == 0) {
      sample_kernel<<<dim3(100, 4), 256, 0, stream>>>(f1t, om, colB, 80, 80, 2, 1, 1);
    } else {
      sample_kernel<<<dim3(100, 4), 256, 0, stream>>>(f0t, om, colB, 160, 160, 4, 3, 3);
    }
    gemm_bt<<<dim3(50, 2, 2), 256, 0, stream>>>(l ? A1 : A0, colB, part, 64, 4096);
    gemm_epilogue<<<dim3(2, 256, 4), 256, 0, stream>>>(part, l ? dcn_b1 : dcn_b0, fsrc, fbuf, 1);
    fsrc = fbuf;
  }
  // res conv as GEMM (M=256, K=2304), epilogue adds f2 (fh)
  nhwc_bf16_kernel<<<dim3(50, 8, 4), 256, 0, stream>>>(fbuf, ft40, 1600);
  im2col40<<<dim3(100, 4), 256, 0, stream>>>(ft40, colB);
  gemm_bt<<<dim3(50, 2, 2), 256, 0, stream>>>(Ares, colB, part, 36, 2304);
  gemm_epilogue<<<dim3(2, 256, 4), 256, 0, stream>>>(part, res_b, f2, out, 0);
}

// Round 4
// 653.599 us; speedup vs baseline: 5.3916x; 1.2737x over previous
//
#include <hip/hip_runtime.h>

#define HW40 1600
typedef unsigned short ushort_t;
typedef __attribute__((ext_vector_type(8))) short short8;
typedef __attribute__((ext_vector_type(4))) short short4v;
typedef __attribute__((ext_vector_type(4))) float f4v;

__device__ __forceinline__ float bu(ushort_t u) {
  union { unsigned i; float f; } x; x.i = ((unsigned)u) << 16; return x.f;
}
__device__ __forceinline__ ushort_t fb(float f) {
  union { float f; unsigned i; } x; x.f = f;
  unsigned r = x.i + 0x7FFFu + ((x.i >> 16) & 1u);
  return (ushort_t)(r >> 16);
}

#define GLD16(g, l)                                                            \
  __builtin_amdgcn_global_load_lds(                                            \
      (const __attribute__((address_space(1))) void*)(g),                      \
      (__attribute__((address_space(3))) void*)(l), 16, 0, 0)

// ---------------------------------------------------------------------------
// 3x3 conv weights [co][cin][3][3] fp32 -> A[co][tap*256+cin] bf16, pad rows.
// ---------------------------------------------------------------------------
__global__ void convert_w9(const float* __restrict__ src, ushort_t* __restrict__ dst,
                           int Cout_src, int Cout_pad) {
  int idx = blockIdx.x * 256 + threadIdx.x;
  if (idx >= Cout_pad * 2304) return;
  int co = idx / 2304;
  int k  = idx - co * 2304;
  int cin = k & 255, tap = k >> 8;
  dst[idx] = (co < Cout_src) ? fb(src[(size_t)co * 2304 + cin * 9 + tap]) : (ushort_t)0;
}

// ---------------------------------------------------------------------------
// dcn weights [co][cin][16] fp32 -> A_bf16 [co][k = i*256 + cin]
// ---------------------------------------------------------------------------
__global__ __launch_bounds__(256) void convert_dcnw(const float* __restrict__ w0,
                                                    const float* __restrict__ w1,
                                                    ushort_t* __restrict__ A0,
                                                    ushort_t* __restrict__ A1) {
  __shared__ float s[4096];
  const int co = blockIdx.x & 255;
  const float* w = (blockIdx.x < 256) ? w0 : w1;
  ushort_t* A = (blockIdx.x < 256) ? A0 : A1;
  const int t = threadIdx.x;
  const float4* wp = (const float4*)(w + (size_t)co * 4096);
#pragma unroll
  for (int q = 0; q < 4; ++q) ((float4*)s)[t + q * 256] = wp[t + q * 256];
  __syncthreads();
  const int i = t >> 4, cb = (t & 15) * 16;
  ushort_t tmp[16];
#pragma unroll
  for (int j = 0; j < 16; ++j) tmp[j] = fb(s[(cb + j) * 16 + i]);
  ushort_t* op = A + (size_t)co * 4096 + t * 16;
  ((uint4*)op)[0] = ((uint4*)tmp)[0];
  ((uint4*)op)[1] = ((uint4*)tmp)[1];
}

// ---------------------------------------------------------------------------
// NCHW fp32 -> NHWC bf16:  xt[b][s][c] = bf16(x[b][c][s])
// ---------------------------------------------------------------------------
__global__ __launch_bounds__(256) void nhwc_bf16_kernel(const float* __restrict__ x,
                                                        ushort_t* __restrict__ xt, int HW) {
  __shared__ float tile[32][33];
  const int s0 = blockIdx.x * 32, c0 = blockIdx.y * 32, b = blockIdx.z;
  const int tx = threadIdx.x & 31, ty = threadIdx.x >> 5;
  const float* xb = x + ((size_t)b * 256 + c0) * HW + s0;
#pragma unroll
  for (int q = 0; q < 4; ++q) tile[ty + q * 8][tx] = xb[(size_t)(ty + q * 8) * HW + tx];
  __syncthreads();
  ushort_t* ob = xt + ((size_t)b * HW + s0) * 256 + c0;
#pragma unroll
  for (int q = 0; q < 4; ++q) {
    int srow = ty + q * 8;
    ob[(size_t)srow * 256 + tx] = fb(tile[tx][srow]);
  }
}

// ---------------------------------------------------------------------------
// im2col for 3x3 s1 p1 on 40x40 NHWC-bf16 feature.
// ---------------------------------------------------------------------------
__global__ __launch_bounds__(256) void im2col40(const ushort_t* __restrict__ ft,
                                                ushort_t* __restrict__ colC) {
  const int b = blockIdx.y;
  const int px0 = blockIdx.x * 16;
  const int t = threadIdx.x;
  const int c8 = (t & 31) * 8;
  const int r  = t >> 5;
  const ushort_t* fb_ = ft + (size_t)b * 1600 * 256;
#pragma unroll 2
  for (int it = 0; it < 18; ++it) {
    int rc = it * 8 + r;
    int px_l = rc / 9;
    int tap  = rc - px_l * 9;
    int p  = px0 + px_l;
    int ph = p / 40, pw = p - (p / 40) * 40;
    int ky = tap / 3, kx = tap - (tap / 3) * 3;
    int y = ph + ky - 1, xq = pw + kx - 1;
    short8 v = (short8)(0);
    if (y >= 0 && y < 40 && xq >= 0 && xq < 40)
      v = *(const short8*)(fb_ + (size_t)(y * 40 + xq) * 256 + c8);
    *(short8*)(colC + ((size_t)(b * 1600 + p) * 2304 + tap * 256 + c8)) = v;
  }
}

// ---------------------------------------------------------------------------
// Sampler: colT[n][k=i*256+cin] bf16 via bilinear gather from NHWC-bf16 xt.
// ---------------------------------------------------------------------------
__global__ __launch_bounds__(256) void sample_kernel(
    const ushort_t* __restrict__ xt, const float* __restrict__ om,
    ushort_t* __restrict__ colT, int Hin, int Win, int stride, int pad, int dil) {
  __shared__ int4  gL[256];
  __shared__ float4 gW[256];
  const int b = blockIdx.y;
  const int px0 = blockIdx.x * 16;
  const int t = threadIdx.x;
  const int HWin = Hin * Win;

  {
    const int px_l = t & 15, i = t >> 4;
    const int p = px0 + px_l;
    const int ph = p / 40, pw = p - (p / 40) * 40;
    const float* omb = om + (size_t)b * 48 * HW40 + p;
    float dy = omb[(2 * i) * HW40];
    float dx = omb[(2 * i + 1) * HW40];
    float mz = omb[(32 + i) * HW40];
    float py = (float)(ph * stride - pad + (i >> 2) * dil) + dy;
    float px = (float)(pw * stride - pad + (i & 3) * dil) + dx;
    float y0f = floorf(py), x0f = floorf(px);
    float ly = py - y0f, lx = px - x0f;
    int y0 = (int)y0f, x0 = (int)x0f;
    int y1 = y0 + 1, x1 = x0 + 1;
    float hy = 1.f - ly, hx = 1.f - lx;
    float w00 = hy * hx * mz, w01 = hy * lx * mz;
    float w10 = ly * hx * mz, w11 = ly * lx * mz;
    if (y0 < 0 || y0 >= Hin) { w00 = 0.f; w01 = 0.f; }
    if (y1 < 0 || y1 >= Hin) { w10 = 0.f; w11 = 0.f; }
    if (x0 < 0 || x0 >= Win) { w00 = 0.f; w10 = 0.f; }
    if (x1 < 0 || x1 >= Win) { w01 = 0.f; w11 = 0.f; }
    int cy0 = min(max(y0, 0), Hin - 1), cy1 = min(max(y1, 0), Hin - 1);
    int cx0 = min(max(x0, 0), Win - 1), cx1 = min(max(x1, 0), Win - 1);
    gL[t] = make_int4((cy0 * Win + cx0) * 256, (cy0 * Win + cx1) * 256,
                      (cy1 * Win + cx0) * 256, (cy1 * Win + cx1) * 256);
    gW[t] = make_float4(w00, w01, w10, w11);
  }
  __syncthreads();

  const ushort_t* xtb = xt + (size_t)b * HWin * 256;
  const int wv = t >> 6, l = t & 63;
  const int half = l >> 5;
  const int cin8 = (l & 31) * 8;

#pragma unroll 2
  for (int it = 0; it < 32; ++it) {
    const int pr = it * 8 + wv * 2 + half;
    const int4 G = gL[pr];
    const float4 W = gW[pr];
    short8 c00 = *(const short8*)(xtb + G.x + cin8);
    short8 c01 = *(const short8*)(xtb + G.y + cin8);
    short8 c10 = *(const short8*)(xtb + G.z + cin8);
    short8 c11 = *(const short8*)(xtb + G.w + cin8);
    short8 rr;
#pragma unroll
    for (int j = 0; j < 8; ++j) {
      float v = W.x * bu((ushort_t)c00[j]) + W.y * bu((ushort_t)c01[j]) +
                W.z * bu((ushort_t)c10[j]) + W.w * bu((ushort_t)c11[j]);
      rr[j] = (short)fb(v);
    }
    const int px_l = pr & 15, i = pr >> 4;
    *(short8*)(colT + ((size_t)(b * 1600 + px0 + px_l) * 4096 + i * 256 + cin8)) = rr;
  }
}

// ---------------------------------------------------------------------------
// Generic bf16 MFMA GEMM, split-K=4, bf16 partials:
//   part[kz][m][n] = sum_k A[m][k]*B[n][k]; block tile MTILE x 128.
// K-chunk swizzle: logical 16B chunk q of row r lives at slot (q+(r>>1))&3
// -> ds_read_b128 worst aliasing 2-way (free, m136). grid (50, M/MTILE, 4).
// ---------------------------------------------------------------------------
template <int MTILE>
__global__ __launch_bounds__(256) void gemm_bt(const ushort_t* __restrict__ A,
                                               const ushort_t* __restrict__ B,
                                               ushort_t* __restrict__ part,
                                               int ksteps, int K) {
  constexpr int FN = (MTILE == 128) ? 4 : 2;
  __shared__ ushort_t sA[MTILE * 32];
  __shared__ ushort_t sB[128 * 32];
  const int nt = blockIdx.x, mt = blockIdx.y, kz = blockIdx.z;
  const int t = threadIdx.x;
  const int wv = t >> 6, l = t & 63;
  const int wm = (MTILE == 128) ? (wv >> 1) : 0;
  const int wn = (MTILE == 128) ? (wv & 1) : wv;

  f4v acc[4][FN];
#pragma unroll
  for (int a = 0; a < 4; ++a)
#pragma unroll
    for (int bb = 0; bb < FN; ++bb) acc[a][bb] = (f4v)(0.f);

  // staging: physical chunk c=t (+256) at row ra(+64); global logical chunk q
  const int ra = t >> 2;
  const int q  = ((t & 3) - (ra >> 1)) & 3;   // same q for row ra and ra+64
  const size_t aoff = (size_t)(mt * MTILE + ra) * K + q * 8;
  const size_t boff = (size_t)(nt * 128 + ra) * K + q * 8;
  ushort_t* lA = sA + t * 8;
  ushort_t* lB = sB + t * 8;

  int k0 = kz * ksteps * 32;
  const int lm = l & 15;
  const int koff = (((l >> 4) + (lm >> 1)) & 3) * 8;  // physical slot for all frag rows

  for (int step = 0; step < ksteps; ++step, k0 += 32) {
    __syncthreads();
    GLD16(A + aoff + k0, lA);
    if (MTILE == 128) GLD16(A + aoff + (size_t)64 * K + k0, lA + 2048);
    GLD16(B + boff + k0, lB);
    GLD16(B + boff + (size_t)64 * K + k0, lB + 2048);
    __syncthreads();
    short8 af[4], bfr[FN];
#pragma unroll
    for (int fm = 0; fm < 4; ++fm)
      af[fm] = *(const short8*)(sA + (wm * 64 + fm * 16 + lm) * 32 + koff);
#pragma unroll
    for (int fn = 0; fn < FN; ++fn)
      bfr[fn] = *(const short8*)(sB + (wn * (16 * FN) + fn * 16 + lm) * 32 + koff);
#pragma unroll
    for (int fm = 0; fm < 4; ++fm)
#pragma unroll
      for (int fn = 0; fn < FN; ++fn)
        acc[fm][fn] = __builtin_amdgcn_mfma_f32_16x16x32_bf16(af[fm], bfr[fn],
                                                              acc[fm][fn], 0, 0, 0);
  }

  const int row_l = (l >> 4) * 4;
  ushort_t* pb = part + (size_t)kz * 1638400;
#pragma unroll
  for (int fm = 0; fm < 4; ++fm) {
#pragma unroll
    for (int fn = 0; fn < FN; ++fn) {
      const int n = nt * 128 + wn * (16 * FN) + fn * 16 + lm;
#pragma unroll
      for (int r = 0; r < 4; ++r) {
        const int m = mt * MTILE + wm * 64 + fm * 16 + row_l + r;
        pb[(size_t)m * 6400 + n] = fb(acc[fm][fn][r]);
      }
    }
  }
}

// ---------------------------------------------------------------------------
// com epilogue: om[(b*48+co)*1600+px] = act(sum4 P + bias), sigmoid co>=32.
// ---------------------------------------------------------------------------
__global__ __launch_bounds__(256) void com_epilogue(const ushort_t* __restrict__ part,
                                                    const float* __restrict__ bias,
                                                    float* __restrict__ om) {
  const int co = blockIdx.y;
  const int n = blockIdx.x * 256 + threadIdx.x;
  const int b = n / 1600, px = n - b * 1600;
  float v = bias[co];
#pragma unroll
  for (int kz = 0; kz < 4; ++kz)
    v += bu(part[(size_t)kz * 1638400 + (size_t)co * 6400 + n]);
  if (co >= 32) v = 1.f / (1.f + expf(-v));
  om[((size_t)b * 48 + co) * 1600 + px] = v;
}

// ---------------------------------------------------------------------------
// GEMM epilogue: dst = (relu? max(sum4+bias,0) : sum4+bias) + src
// ---------------------------------------------------------------------------
__global__ __launch_bounds__(256) void gemm_epilogue(const ushort_t* __restrict__ part,
                                                     const float* __restrict__ bias,
                                                     const float* __restrict__ src,
                                                     float* __restrict__ dst, int relu) {
  const int co = blockIdx.y, b = blockIdx.z;
  const int idx = blockIdx.x * 256 + threadIdx.x;
  if (idx >= 400) return;
  const int p = idx * 4;
  const size_t n = (size_t)b * 1600 + p;
  float a[4] = {0.f, 0.f, 0.f, 0.f};
#pragma unroll
  for (int kz = 0; kz < 4; ++kz) {
    short4v pp = *(const short4v*)(part + (size_t)kz * 1638400 + (size_t)co * 6400 + n);
#pragma unroll
    for (int j = 0; j < 4; ++j) a[j] += bu((ushort_t)pp[j]);
  }
  float bv = bias[co];
  const size_t fo = ((size_t)b * 256 + co) * 1600 + p;
  float4 s = *(const float4*)(src + fo);
  float4 o;
  if (relu) {
    o.x = fmaxf(a[0] + bv, 0.f) + s.x;
    o.y = fmaxf(a[1] + bv, 0.f) + s.y;
    o.z = fmaxf(a[2] + bv, 0.f) + s.z;
    o.w = fmaxf(a[3] + bv, 0.f) + s.w;
  } else {
    o.x = a[0] + bv + s.x;
    o.y = a[1] + bv + s.y;
    o.z = a[2] + bv + s.z;
    o.w = a[3] + bv + s.w;
  }
  *(float4*)(dst + fo) = o;
}

// ---------------------------------------------------------------------------
extern "C" void kernel_launch(void* const* d_in, const int* in_sizes, int n_in,
                              void* d_out, int out_size, void* d_ws, size_t ws_size,
                              hipStream_t stream) {
  (void)in_sizes; (void)n_in; (void)out_size; (void)ws_size;
  const float* f0     = (const float*)d_in[0];
  const float* f1     = (const float*)d_in[1];
  const float* f2     = (const float*)d_in[2];
  const float* com_w0 = (const float*)d_in[3];
  const float* com_b0 = (const float*)d_in[4];
  const float* com_w1 = (const float*)d_in[5];
  const float* com_b1 = (const float*)d_in[6];
  const float* dcn_w0 = (const float*)d_in[7];
  const float* dcn_b0 = (const float*)d_in[8];
  const float* dcn_w1 = (const float*)d_in[9];
  const float* dcn_b1 = (const float*)d_in[10];
  const float* res_w  = (const float*)d_in[11];
  const float* res_b  = (const float*)d_in[12];
  float* out = (float*)d_out;
  float* ws  = (float*)d_ws;

  // ws layout (float offsets); total ~37.2M floats ~= 149 MB (same as R3)
  float*    om    = ws + 0;          //   307,200
  float*    fbuf  = ws + 310000;     // 1,638,400
  ushort_t* A0    = (ushort_t*)(ws + 1950000);   // 1,048,576 u16
  ushort_t* A1    = (ushort_t*)(ws + 2480000);   // 1,048,576 u16
  ushort_t* Acom0 = (ushort_t*)(ws + 3010000);   //   147,456 u16 (64x2304)
  ushort_t* Acom1 = (ushort_t*)(ws + 3160000);   //   147,456 u16
  ushort_t* Ares  = (ushort_t*)(ws + 3310000);   //   589,824 u16 (256x2304)
  ushort_t* ft40  = (ushort_t*)(ws + 3610000);   // 1,638,400 u16
  ushort_t* f1t   = (ushort_t*)(ws + 4430000);   // 6,553,600 u16
  ushort_t* f0t   = (ushort_t*)(ws + 7710000);   // 26,214,400 u16
  ushort_t* colB  = (ushort_t*)(ws + 20820000);  // 26,214,400 u16 (colC & colT share)
  ushort_t* part  = (ushort_t*)(ws + 33930000);  // 6,553,600 u16 (4 bf16 slices)

  convert_w9<<<(64 * 2304 + 255) / 256, 256, 0, stream>>>(com_w0, Acom0, 48, 64);
  convert_w9<<<(64 * 2304 + 255) / 256, 256, 0, stream>>>(com_w1, Acom1, 48, 64);
  convert_w9<<<(256 * 2304 + 255) / 256, 256, 0, stream>>>(res_w, Ares, 256, 256);
  convert_dcnw<<<512, 256, 0, stream>>>(dcn_w0, dcn_w1, A0, A1);
  nhwc_bf16_kernel<<<dim3(200, 8, 4), 256, 0, stream>>>(f1, f1t, 6400);
  nhwc_bf16_kernel<<<dim3(800, 8, 4), 256, 0, stream>>>(f0, f0t, 25600);

  const float* fsrc = f2;
  for (int s = 0; s < 4; ++s) {
    int l = s & 1;
    // com conv as GEMM (M=48 padded to 64, K=2304)
    nhwc_bf16_kernel<<<dim3(50, 8, 4), 256, 0, stream>>>(fsrc, ft40, 1600);
    im2col40<<<dim3(100, 4), 256, 0, stream>>>(ft40, colB);
    gemm_bt<64><<<dim3(50, 1, 4), 256, 0, stream>>>(l ? Acom1 : Acom0, colB, part, 18, 2304);
    com_epilogue<<<dim3(25, 48), 256, 0, stream>>>(part, l ? com_b1 : com_b0, om);
    // deformable conv (K=4096)
    if (l == 0) {
      sample_kernel<<<dim3(100, 4), 256, 0, stream>>>(f1t, om, colB, 80, 80, 2, 1, 1);
    } else {
      sample_kernel<<<dim3(100, 4), 256, 0, stream>>>(f0t, om, colB, 160, 160, 4, 3, 3);
    }
    gemm_bt<128><<<dim3(50, 2, 4), 256, 0, stream>>>(l ? A1 : A0, colB, part, 32, 4096);
    gemm_epilogue<<<dim3(2, 256, 4), 256, 0, stream>>>(part, l ? dcn_b1 : dcn_b0, fsrc, fbuf, 1);
    fsrc = fbuf;
  }
  // res conv as GEMM (M=256, K=2304), epilogue adds f2 (fh)
  nhwc_bf16_kernel<<<dim3(50, 8, 4), 256, 0, stream>>>(fbuf, ft40, 1600);
  im2col40<<<dim3(100, 4), 256, 0, stream>>>(ft40, colB);
  gemm_bt<128><<<dim3(50, 2, 4), 256, 0, stream>>>(Ares, colB, part, 18, 2304);
  gemm_epilogue<<<dim3(2, 256, 4), 256, 0, stream>>>(part, res_b, f2, out, 0);
}